// Round 1
// baseline (205.191 us; speedup 1.0000x reference)
//
#include <hip/hip_runtime.h>
#include <hip/hip_bf16.h>

// ---------------- types ----------------
typedef __bf16 bf16x8 __attribute__((__ext_vector_type__(8)));
typedef __bf16 bf16x4 __attribute__((__ext_vector_type__(4)));
typedef float  f32x4  __attribute__((__ext_vector_type__(4)));

#define MFMA16(a, b, c) __builtin_amdgcn_mfma_f32_16x16x32_bf16((a), (b), (c), 0, 0, 0)

static constexpr int   NSEQ  = 2304;   // 48*48
static constexpr int   CDIM  = 256;
static constexpr float SCALE = 0.17677669529663687f;  // 32^-0.5

// ---------------- weight transpose + f32->bf16 ----------------
// in: f32 [K][N] row-major  ->  out: bf16 [N][K]
__global__ __launch_bounds__(256) void transpose_w_kernel(
    const float* __restrict__ wqkv, const float* __restrict__ wproj,
    const float* __restrict__ wfc1, const float* __restrict__ wfc2,
    __hip_bfloat16* __restrict__ oqkv, __hip_bfloat16* __restrict__ oproj,
    __hip_bfloat16* __restrict__ ofc1, __hip_bfloat16* __restrict__ ofc2)
{
    int b = blockIdx.x;
    const float* src; __hip_bfloat16* dst; int K, N, t;
    if (b < 192)      { src = wqkv;  dst = oqkv;  K = 256;  N = 768;  t = b;       }
    else if (b < 256) { src = wproj; dst = oproj; K = 256;  N = 256;  t = b - 192; }
    else if (b < 512) { src = wfc1;  dst = ofc1;  K = 256;  N = 1024; t = b - 256; }
    else              { src = wfc2;  dst = ofc2;  K = 1024; N = 256;  t = b - 512; }
    int ntn = N >> 5;
    int tk = t / ntn, tn = t % ntn;
    __shared__ float tile[32][33];
    int tid = threadIdx.x;
    int tx = tid & 31, ty = tid >> 5;   // 32 x 8
    #pragma unroll
    for (int r = 0; r < 4; ++r)
        tile[ty + 8 * r][tx] = src[(size_t)(tk * 32 + ty + 8 * r) * N + tn * 32 + tx];
    __syncthreads();
    #pragma unroll
    for (int r = 0; r < 4; ++r)
        dst[(size_t)(tn * 32 + ty + 8 * r) * K + tk * 32 + tx] =
            __float2bfloat16(tile[tx][ty + 8 * r]);
}

// ---------------- LayerNorm (f32 in -> bf16 out) ----------------
__global__ __launch_bounds__(256) void ln_kernel(
    const float* __restrict__ x, const float* __restrict__ g,
    const float* __restrict__ b, __hip_bfloat16* __restrict__ o)
{
    int row = blockIdx.x, tid = threadIdx.x;
    float v = x[(size_t)row * 256 + tid];
    float s = v, s2 = v * v;
    #pragma unroll
    for (int m = 32; m >= 1; m >>= 1) {
        s  += __shfl_xor(s,  m);
        s2 += __shfl_xor(s2, m);
    }
    __shared__ float rs_[4], rs2_[4];
    int w = tid >> 6;
    if ((tid & 63) == 0) { rs_[w] = s; rs2_[w] = s2; }
    __syncthreads();
    s  = rs_[0]  + rs_[1]  + rs_[2]  + rs_[3];
    s2 = rs2_[0] + rs2_[1] + rs2_[2] + rs2_[3];
    float mu   = s * (1.f / 256.f);
    float var  = s2 * (1.f / 256.f) - mu * mu;
    float rstd = rsqrtf(var + 1e-5f);
    o[(size_t)row * 256 + tid] = __float2bfloat16((v - mu) * rstd * g[tid] + b[tid]);
}

// ---------------- generic GEMM: C[M,N] = A[M,K] @ BT[N,K]^T, + epilogue ----------------
// EPI 0: QKV split/scale  1: proj+bias+residual(f32 out)  2: fc1+bias+gelu(bf16)  3: fc2+bias+residual(f32 out)
template <int EPI, int NN, int KK>
__global__ __launch_bounds__(256) void gemm_kernel(
    const __hip_bfloat16* __restrict__ A,
    const __hip_bfloat16* __restrict__ BT,
    const float* __restrict__ bias,
    const float* __restrict__ resid,
    void* __restrict__ out0, void* __restrict__ out1, void* __restrict__ out2)
{
    int bm = blockIdx.y * 64, bn = blockIdx.x * 64;
    int tid = threadIdx.x;
    int w = tid >> 6, lane = tid & 63, l15 = lane & 15, g = lane >> 4;
    int wr = w >> 1, wc = w & 1;

    f32x4 acc[2][2];
    #pragma unroll
    for (int i = 0; i < 2; ++i)
        #pragma unroll
        for (int j = 0; j < 2; ++j) acc[i][j] = (f32x4){0.f, 0.f, 0.f, 0.f};

    const __hip_bfloat16* Arow = A  + (size_t)(bm + 32 * wr + l15) * KK + 8 * g;
    const __hip_bfloat16* Brow = BT + (size_t)(bn + 32 * wc + l15) * KK + 8 * g;

    for (int kb = 0; kb < KK; kb += 32) {
        bf16x8 a0 = *reinterpret_cast<const bf16x8*>(Arow + kb);
        bf16x8 a1 = *reinterpret_cast<const bf16x8*>(Arow + (size_t)16 * KK + kb);
        bf16x8 b0 = *reinterpret_cast<const bf16x8*>(Brow + kb);
        bf16x8 b1 = *reinterpret_cast<const bf16x8*>(Brow + (size_t)16 * KK + kb);
        acc[0][0] = MFMA16(a0, b0, acc[0][0]);
        acc[0][1] = MFMA16(a0, b1, acc[0][1]);
        acc[1][0] = MFMA16(a1, b0, acc[1][0]);
        acc[1][1] = MFMA16(a1, b1, acc[1][1]);
    }

    #pragma unroll
    for (int fi = 0; fi < 2; ++fi)
    #pragma unroll
    for (int fj = 0; fj < 2; ++fj)
    #pragma unroll
    for (int j = 0; j < 4; ++j) {
        int m = bm + 32 * wr + 16 * fi + 4 * g + j;
        int n = bn + 32 * wc + 16 * fj + l15;
        float v = acc[fi][fj][j];
        if constexpr (EPI == 0) {
            int which = n >> 8, h = (n >> 5) & 7, d = n & 31;
            __hip_bfloat16* Qb = (__hip_bfloat16*)out0;
            __hip_bfloat16* Kb = (__hip_bfloat16*)out1;
            __hip_bfloat16* Vt = (__hip_bfloat16*)out2;
            if (which == 0)      Qb[((size_t)(h * NSEQ + m) << 5) + d] = __float2bfloat16(v * SCALE);
            else if (which == 1) Kb[((size_t)(h * NSEQ + m) << 5) + d] = __float2bfloat16(v);
            else                 Vt[(size_t)((h << 5) + d) * NSEQ + m] = __float2bfloat16(v);
        } else if constexpr (EPI == 1) {
            float r = v + bias[n] + resid[(size_t)m * 256 + n];
            ((float*)out0)[(size_t)m * 256 + n] = r;
        } else if constexpr (EPI == 2) {
            float r = v + bias[n];
            r = 0.5f * r * (1.f + erff(r * 0.70710678118654752f));
            ((__hip_bfloat16*)out0)[(size_t)m * NN + n] = __float2bfloat16(r);
        } else {
            float r = v + bias[n] + resid[(size_t)m * 256 + n];
            ((float*)out0)[(size_t)m * 256 + n] = r;
        }
    }
}

// ---------------- fused flash attention with on-the-fly relative-position bias ----------------
// grid: 8 heads * 36 q-tiles(64 rows). block: 512 thr = 8 waves.
// wave w: q-subtile (w&3)*16 rows, kv-half (w>>2). Halves merged via LDS at the end.
__global__ __launch_bounds__(512) void attn_kernel(
    const __hip_bfloat16* __restrict__ Q,
    const __hip_bfloat16* __restrict__ Kb,
    const __hip_bfloat16* __restrict__ Vt,   // [8][32][2304]
    const float* __restrict__ btab,          // [9025][8]
    __hip_bfloat16* __restrict__ O)          // [2304][256]
{
    __shared__ float bias_l[9025];
    __shared__ __hip_bfloat16 P_lds[8][16][72];
    __shared__ float comb_O[4][16][32];
    __shared__ float comb_m[4][16];
    __shared__ float comb_l[4][16];

    int bid = blockIdx.x;
    int h = bid / 36, qt = bid % 36;
    int tid = threadIdx.x;
    int w = tid >> 6, lane = tid & 63, l15 = lane & 15, g = lane >> 4;
    int qsub = w & 3, half = w >> 2;

    for (int i = tid; i < 9025; i += 512) bias_l[i] = btab[(size_t)i * 8 + h];
    __syncthreads();

    int qrow = qt * 64 + qsub * 16 + l15;
    bf16x8 qf = *reinterpret_cast<const bf16x8*>(Q + ((size_t)(h * NSEQ + qrow) << 5) + 8 * g);
    int i1 = qrow / 48, j1 = qrow - i1 * 48;

    float m_st = -1e30f, l_st = 0.f;
    f32x4 o0 = (f32x4){0.f, 0.f, 0.f, 0.f};
    f32x4 o1 = (f32x4){0.f, 0.f, 0.f, 0.f};
    const f32x4 zero = (f32x4){0.f, 0.f, 0.f, 0.f};

    for (int kt = 18 * half; kt < 18 * half + 18; ++kt) {
        int kv0 = kt * 64;
        f32x4 st[4];
        #pragma unroll
        for (int s = 0; s < 4; ++s) {
            bf16x8 kf = *reinterpret_cast<const bf16x8*>(
                Kb + ((size_t)(h * NSEQ + kv0 + 16 * s + l15) << 5) + 8 * g);
            st[s] = MFMA16(kf, qf, zero);   // S^T[kv][q]: row=kv, col=q(l15)
        }
        // bias add + tile max
        float p[4][4];
        float mx = -1e30f;
        #pragma unroll
        for (int s = 0; s < 4; ++s) {
            int kvb = kv0 + 16 * s + 4 * g;
            int i2 = kvb / 48, j2b = kvb - i2 * 48;
            #pragma unroll
            for (int j = 0; j < 4; ++j) {
                int j2 = j2b + j;
                int wrap = (j2 >= 48) ? 1 : 0;
                int ii = i2 + wrap;
                j2 -= 48 * wrap;
                int idx = (i1 - ii + 47) * 95 + (j1 - j2 + 47);
                float sv = st[s][j] + bias_l[idx];
                p[s][j] = sv;
                mx = fmaxf(mx, sv);
            }
        }
        mx = fmaxf(mx, __shfl_xor(mx, 16));
        mx = fmaxf(mx, __shfl_xor(mx, 32));
        float mn = fmaxf(m_st, mx);
        float rs = 0.f;
        #pragma unroll
        for (int s = 0; s < 4; ++s)
            #pragma unroll
            for (int j = 0; j < 4; ++j) {
                float e = __expf(p[s][j] - mn);
                p[s][j] = e;
                rs += e;
            }
        rs += __shfl_xor(rs, 16);
        rs += __shfl_xor(rs, 32);
        float sc = __expf(m_st - mn);
        l_st = l_st * sc + rs;
        m_st = mn;
        // rescale O accumulators (rows r = 4g+j; scale lives at lane r)
        float scr[4];
        #pragma unroll
        for (int j = 0; j < 4; ++j) scr[j] = __shfl(sc, 4 * g + j);
        #pragma unroll
        for (int j = 0; j < 4; ++j) { o0[j] *= scr[j]; o1[j] *= scr[j]; }
        // P -> LDS (store transposed back to [q][kv])
        #pragma unroll
        for (int s = 0; s < 4; ++s) {
            bf16x4 pk = { (__bf16)p[s][0], (__bf16)p[s][1], (__bf16)p[s][2], (__bf16)p[s][3] };
            *reinterpret_cast<bf16x4*>(&P_lds[w][l15][16 * s + 4 * g]) = pk;
        }
        // PV
        #pragma unroll
        for (int hh = 0; hh < 2; ++hh) {
            bf16x8 pf = *reinterpret_cast<const bf16x8*>(&P_lds[w][l15][32 * hh + 8 * g]);
            #pragma unroll
            for (int t = 0; t < 2; ++t) {
                bf16x8 vf = *reinterpret_cast<const bf16x8*>(
                    Vt + (size_t)((h << 5) + 16 * t + l15) * NSEQ + kv0 + 32 * hh + 8 * g);
                if (t == 0) o0 = MFMA16(pf, vf, o0);
                else        o1 = MFMA16(pf, vf, o1);
            }
        }
    }

    // merge the two kv-halves
    if (half == 1) {
        #pragma unroll
        for (int t = 0; t < 2; ++t)
            #pragma unroll
            for (int j = 0; j < 4; ++j)
                comb_O[qsub][4 * g + j][16 * t + l15] = (t == 0 ? o0[j] : o1[j]);
        if (g == 0) { comb_m[qsub][l15] = m_st; comb_l[qsub][l15] = l_st; }
    }
    __syncthreads();
    if (half == 0) {
        float m2 = comb_m[qsub][l15], l2 = comb_l[qsub][l15];
        float M  = fmaxf(m_st, m2);
        float a1 = __expf(m_st - M), a2 = __expf(m2 - M);
        float linv = 1.f / (a1 * l_st + a2 * l2);
        float a1r[4], a2r[4], lr[4];
        #pragma unroll
        for (int j = 0; j < 4; ++j) {
            int r = 4 * g + j;
            a1r[j] = __shfl(a1, r);
            a2r[j] = __shfl(a2, r);
            lr[j]  = __shfl(linv, r);
        }
        #pragma unroll
        for (int t = 0; t < 2; ++t)
            #pragma unroll
            for (int j = 0; j < 4; ++j) {
                float v1 = (t == 0 ? o0[j] : o1[j]);
                float v = (v1 * a1r[j] + comb_O[qsub][4 * g + j][16 * t + l15] * a2r[j]) * lr[j];
                O[(size_t)(qt * 64 + qsub * 16 + 4 * g + j) * 256 + (h << 5) + 16 * t + l15] =
                    __float2bfloat16(v);
            }
    }
}

// ---------------- launch ----------------
extern "C" void kernel_launch(void* const* d_in, const int* in_sizes, int n_in,
                              void* d_out, int out_size, void* d_ws, size_t ws_size,
                              hipStream_t stream)
{
    const float* x      = (const float*)d_in[0];
    const float* gamma1 = (const float*)d_in[1];
    const float* beta1  = (const float*)d_in[2];
    const float* w_qkv  = (const float*)d_in[3];
    const float* w_proj = (const float*)d_in[4];
    const float* b_proj = (const float*)d_in[5];
    const float* btab   = (const float*)d_in[6];
    const float* gamma2 = (const float*)d_in[7];
    const float* beta2  = (const float*)d_in[8];
    const float* w_fc1  = (const float*)d_in[9];
    const float* b_fc1  = (const float*)d_in[10];
    const float* w_fc2  = (const float*)d_in[11];
    const float* b_fc2  = (const float*)d_in[12];
    // d_in[13] rel_idx: recomputed analytically in-kernel.

    char* ws = (char*)d_ws;
    size_t off = 0;
    auto alloc = [&](size_t bytes) -> void* {
        void* p = ws + off;
        off += (bytes + 255) & ~(size_t)255;
        return p;
    };
    __hip_bfloat16* wqkvT = (__hip_bfloat16*)alloc((size_t)768 * 256 * 2);
    __hip_bfloat16* wprojT= (__hip_bfloat16*)alloc((size_t)256 * 256 * 2);
    __hip_bfloat16* wfc1T = (__hip_bfloat16*)alloc((size_t)1024 * 256 * 2);
    __hip_bfloat16* wfc2T = (__hip_bfloat16*)alloc((size_t)256 * 1024 * 2);
    __hip_bfloat16* t1    = (__hip_bfloat16*)alloc((size_t)NSEQ * 256 * 2);
    __hip_bfloat16* Qb    = (__hip_bfloat16*)alloc((size_t)8 * NSEQ * 32 * 2);
    __hip_bfloat16* Kbuf  = (__hip_bfloat16*)alloc((size_t)8 * NSEQ * 32 * 2);
    __hip_bfloat16* Vt    = (__hip_bfloat16*)alloc((size_t)8 * 32 * NSEQ * 2);
    __hip_bfloat16* Ob    = (__hip_bfloat16*)alloc((size_t)NSEQ * 256 * 2);
    float*          x2    = (float*)alloc((size_t)NSEQ * 256 * 4);
    __hip_bfloat16* t2    = (__hip_bfloat16*)alloc((size_t)NSEQ * 256 * 2);
    __hip_bfloat16* hb    = (__hip_bfloat16*)alloc((size_t)NSEQ * 1024 * 2);

    transpose_w_kernel<<<dim3(768), dim3(256), 0, stream>>>(
        w_qkv, w_proj, w_fc1, w_fc2, wqkvT, wprojT, wfc1T, wfc2T);

    ln_kernel<<<dim3(NSEQ), dim3(256), 0, stream>>>(x, gamma1, beta1, t1);

    gemm_kernel<0, 768, 256><<<dim3(12, 36), dim3(256), 0, stream>>>(
        t1, wqkvT, nullptr, nullptr, Qb, Kbuf, Vt);

    attn_kernel<<<dim3(288), dim3(512), 0, stream>>>(Qb, Kbuf, Vt, btab, Ob);

    gemm_kernel<1, 256, 256><<<dim3(4, 36), dim3(256), 0, stream>>>(
        Ob, wprojT, b_proj, x, x2, nullptr, nullptr);

    ln_kernel<<<dim3(NSEQ), dim3(256), 0, stream>>>(x2, gamma2, beta2, t2);

    gemm_kernel<2, 1024, 256><<<dim3(16, 36), dim3(256), 0, stream>>>(
        t2, wfc1T, b_fc1, nullptr, hb, nullptr, nullptr);

    gemm_kernel<3, 256, 1024><<<dim3(4, 36), dim3(256), 0, stream>>>(
        hb, wfc2T, b_fc2, x2, d_out, nullptr, nullptr);
}

// Round 2
// 194.871 us; speedup vs baseline: 1.0530x; 1.0530x over previous
//
#include <hip/hip_runtime.h>
#include <hip/hip_bf16.h>

// ---------------- types ----------------
typedef __bf16 bf16x8 __attribute__((__ext_vector_type__(8)));
typedef __bf16 bf16x4 __attribute__((__ext_vector_type__(4)));
typedef float  f32x4  __attribute__((__ext_vector_type__(4)));

#define MFMA16(a, b, c) __builtin_amdgcn_mfma_f32_16x16x32_bf16((a), (b), (c), 0, 0, 0)

static constexpr int   NSEQ  = 2304;   // 48*48
static constexpr float SCALE = 0.17677669529663687f;  // 32^-0.5

// ---------------- weight transpose + f32->bf16 (+ bias table transpose) ----------------
__global__ __launch_bounds__(256) void transpose_w_kernel(
    const float* __restrict__ wqkv, const float* __restrict__ wproj,
    const float* __restrict__ wfc1, const float* __restrict__ wfc2,
    const float* __restrict__ btab,
    __hip_bfloat16* __restrict__ oqkv, __hip_bfloat16* __restrict__ oproj,
    __hip_bfloat16* __restrict__ ofc1, __hip_bfloat16* __restrict__ ofc2,
    float* __restrict__ btabT)
{
    int b = blockIdx.x;
    int tid = threadIdx.x;
    if (b >= 768) {   // bias table [9025][8] -> [8][9025]
        int base = (b - 768) * 1024;
        for (int k = tid; k < 1024; k += 256) {
            int e = base + k;
            if (e < 72200) { int i = e >> 3, hh = e & 7; btabT[hh * 9025 + i] = btab[e]; }
        }
        return;
    }
    const float* src; __hip_bfloat16* dst; int K, N, t;
    if (b < 192)      { src = wqkv;  dst = oqkv;  K = 256;  N = 768;  t = b;       }
    else if (b < 256) { src = wproj; dst = oproj; K = 256;  N = 256;  t = b - 192; }
    else if (b < 512) { src = wfc1;  dst = ofc1;  K = 256;  N = 1024; t = b - 256; }
    else              { src = wfc2;  dst = ofc2;  K = 1024; N = 256;  t = b - 512; }
    int ntn = N >> 5;
    int tk = t / ntn, tn = t % ntn;
    __shared__ float tile[32][33];
    int tx = tid & 31, ty = tid >> 5;   // 32 x 8
    #pragma unroll
    for (int r = 0; r < 4; ++r)
        tile[ty + 8 * r][tx] = src[(size_t)(tk * 32 + ty + 8 * r) * N + tn * 32 + tx];
    __syncthreads();
    #pragma unroll
    for (int r = 0; r < 4; ++r)
        dst[(size_t)(tn * 32 + ty + 8 * r) * K + tk * 32 + tx] =
            __float2bfloat16(tile[tx][ty + 8 * r]);
}

// ---------------- LayerNorm (f32 in -> bf16 out) ----------------
__global__ __launch_bounds__(256) void ln_kernel(
    const float* __restrict__ x, const float* __restrict__ g,
    const float* __restrict__ b, __hip_bfloat16* __restrict__ o)
{
    int row = blockIdx.x, tid = threadIdx.x;
    float v = x[(size_t)row * 256 + tid];
    float s = v, s2 = v * v;
    #pragma unroll
    for (int m = 32; m >= 1; m >>= 1) {
        s  += __shfl_xor(s,  m);
        s2 += __shfl_xor(s2, m);
    }
    __shared__ float rs_[4], rs2_[4];
    int w = tid >> 6;
    if ((tid & 63) == 0) { rs_[w] = s; rs2_[w] = s2; }
    __syncthreads();
    s  = rs_[0]  + rs_[1]  + rs_[2]  + rs_[3];
    s2 = rs2_[0] + rs2_[1] + rs2_[2] + rs2_[3];
    float mu   = s * (1.f / 256.f);
    float var  = s2 * (1.f / 256.f) - mu * mu;
    float rstd = rsqrtf(var + 1e-5f);
    o[(size_t)row * 256 + tid] = __float2bfloat16((v - mu) * rstd * g[tid] + b[tid]);
}

// ---------------- generic GEMM: C[M,N] = A[M,K] @ BT[N,K]^T, + epilogue ----------------
// EPI 0: QKV split/scale (V via LDS transpose)  1: proj+bias+resid  2: fc1+bias+gelu  3: fc2+bias+resid
template <int EPI, int NN, int KK, int FM, int FN, int WR, int WC>
__global__ __launch_bounds__(256) void gemm_kernel(
    const __hip_bfloat16* __restrict__ A,
    const __hip_bfloat16* __restrict__ BT,
    const float* __restrict__ bias,
    const float* __restrict__ resid,
    void* __restrict__ out0, void* __restrict__ out1, void* __restrict__ out2)
{
    constexpr int BM = WR * FM * 16, BN = WC * FN * 16;
    int bm = blockIdx.y * BM, bn = blockIdx.x * BN;
    int tid = threadIdx.x;
    int w = tid >> 6, lane = tid & 63, l15 = lane & 15, g = lane >> 4;
    int wr = w / WC, wc = w % WC;

    f32x4 acc[FM][FN];
    #pragma unroll
    for (int i = 0; i < FM; ++i)
        #pragma unroll
        for (int j = 0; j < FN; ++j) acc[i][j] = (f32x4){0.f, 0.f, 0.f, 0.f};

    const __hip_bfloat16* Arow = A  + (size_t)(bm + wr * FM * 16 + l15) * KK + 8 * g;
    const __hip_bfloat16* Brow = BT + (size_t)(bn + wc * FN * 16 + l15) * KK + 8 * g;

    #pragma unroll
    for (int kb = 0; kb < KK; kb += 32) {
        bf16x8 af[FM], bfr[FN];
        #pragma unroll
        for (int i = 0; i < FM; ++i)
            af[i] = *reinterpret_cast<const bf16x8*>(Arow + (size_t)16 * i * KK + kb);
        #pragma unroll
        for (int j = 0; j < FN; ++j)
            bfr[j] = *reinterpret_cast<const bf16x8*>(Brow + (size_t)16 * j * KK + kb);
        #pragma unroll
        for (int i = 0; i < FM; ++i)
            #pragma unroll
            for (int j = 0; j < FN; ++j)
                acc[i][j] = MFMA16(af[i], bfr[j], acc[i][j]);
    }

    if constexpr (EPI == 0) {
        if (bn >= 512) {   // V blocks: LDS transpose for coalesced [h][d][n] stores
            __shared__ float vtile[64][65];
            #pragma unroll
            for (int fi = 0; fi < FM; ++fi)
            #pragma unroll
            for (int fj = 0; fj < FN; ++fj)
            #pragma unroll
            for (int j = 0; j < 4; ++j)
                vtile[32 * wr + 16 * fi + 4 * g + j][32 * wc + 16 * fj + l15] = acc[fi][fj][j];
            __syncthreads();
            __hip_bfloat16* Vt = (__hip_bfloat16*)out2;
            for (int e = tid; e < 4096; e += 256) {
                int mi = e & 63, ni = e >> 6;
                int n = bn + ni;
                int h = (n >> 5) & 7, d = n & 31;
                Vt[(size_t)(h * 32 + d) * NSEQ + bm + mi] = __float2bfloat16(vtile[mi][ni]);
            }
            return;
        }
    }

    #pragma unroll
    for (int fi = 0; fi < FM; ++fi)
    #pragma unroll
    for (int fj = 0; fj < FN; ++fj)
    #pragma unroll
    for (int j = 0; j < 4; ++j) {
        int m = bm + wr * FM * 16 + 16 * fi + 4 * g + j;
        int n = bn + wc * FN * 16 + 16 * fj + l15;
        float v = acc[fi][fj][j];
        if constexpr (EPI == 0) {
            int which = n >> 8, h = (n >> 5) & 7, d = n & 31;
            __hip_bfloat16* Qb = (__hip_bfloat16*)out0;
            __hip_bfloat16* Kb = (__hip_bfloat16*)out1;
            if (which == 0)      Qb[((size_t)(h * NSEQ + m) << 5) + d] = __float2bfloat16(v * SCALE);
            else                 Kb[((size_t)(h * NSEQ + m) << 5) + d] = __float2bfloat16(v);
        } else if constexpr (EPI == 1) {
            ((float*)out0)[(size_t)m * 256 + n] = v + bias[n] + resid[(size_t)m * 256 + n];
        } else if constexpr (EPI == 2) {
            float r = v + bias[n];
            r = 0.5f * r * (1.f + erff(r * 0.70710678118654752f));
            ((__hip_bfloat16*)out0)[(size_t)m * NN + n] = __float2bfloat16(r);
        } else {
            ((float*)out0)[(size_t)m * 256 + n] = v + bias[n] + resid[(size_t)m * 256 + n];
        }
    }
}

// ---------------- flash attention, kv split 4 ways across blocks ----------------
// grid: 8 heads * 36 q-tiles * 4 kv-quarters = 1152 blocks; 4 waves (one 16-row q-subtile each).
// Writes unnormalized partial O (bf16) + m,l (f32); merged by attn_merge_kernel.
__global__ __launch_bounds__(256, 5) void attn_kernel(
    const __hip_bfloat16* __restrict__ Q,
    const __hip_bfloat16* __restrict__ Kb,
    const __hip_bfloat16* __restrict__ Vt,     // [8][32][2304]
    const float* __restrict__ btabT,           // [8][9025]
    float* __restrict__ Pm, float* __restrict__ Pl,
    __hip_bfloat16* __restrict__ PO)           // [4][8][2304][32]
{
    __shared__ float bias_l[14 * 96];
    __shared__ __hip_bfloat16 P_lds[4][16][72];

    int bid = blockIdx.x;
    int h = bid / 144;
    int r = bid - h * 144;
    int qt = r >> 2, kvq = r & 3;
    int tid = threadIdx.x;
    int w = tid >> 6, lane = tid & 63, l15 = lane & 15, g = lane >> 4;

    int q0 = qt * 64;
    int i1min = q0 / 48, i1max = (q0 + 63) / 48;
    int i2min = kvq * 12;
    int dimin = i1min - (i2min + 11);
    int nrow = (i1max - i1min) + 12;   // <= 14

    for (int i = tid; i < nrow * 95; i += 256) {
        int rr = i / 95, cc = i - rr * 95;
        bias_l[rr * 96 + cc] = btabT[h * 9025 + (dimin + rr + 47) * 95 + cc];
    }
    __syncthreads();

    int qrow = q0 + w * 16 + l15;
    int i1 = qrow / 48, j1 = qrow - i1 * 48;
    int laneBase = (i1 - dimin) * 96 + j1 + 47;
    bf16x8 qf = *reinterpret_cast<const bf16x8*>(Q + ((size_t)(h * NSEQ + qrow) << 5) + 8 * g);

    float m_st = -1e30f, l_st = 0.f;
    f32x4 o0 = (f32x4){0.f, 0.f, 0.f, 0.f};
    f32x4 o1 = (f32x4){0.f, 0.f, 0.f, 0.f};
    const f32x4 zero = (f32x4){0.f, 0.f, 0.f, 0.f};
    int kvbase = kvq * 576;

    for (int t = 0; t < 9; ++t) {
        int kv0 = kvbase + t * 64;
        // V loads early (independent of all compute this tile)
        bf16x8 vf[4];
        #pragma unroll
        for (int u = 0; u < 4; ++u) {
            int dt = u >> 1, hh = u & 1;
            vf[u] = *reinterpret_cast<const bf16x8*>(
                Vt + (size_t)((h << 5) + 16 * dt + l15) * NSEQ + kv0 + 32 * hh + 8 * g);
        }
        f32x4 st[4];
        #pragma unroll
        for (int s = 0; s < 4; ++s) {
            bf16x8 kf = *reinterpret_cast<const bf16x8*>(
                Kb + ((size_t)(h * NSEQ + kv0 + 16 * s + l15) << 5) + 8 * g);
            st[s] = MFMA16(kf, qf, zero);   // S^T[kv][q]: col q = l15
        }
        // bias add + tile max (in place)
        float mx = -1e30f;
        #pragma unroll
        for (int s = 0; s < 4; ++s) {
            int kvb = kv0 + 16 * s + 4 * g;
            int i2 = kvb / 48;
            int j2b = kvb - 48 * i2;
            int sub = laneBase - i2 * 96 - j2b;
            #pragma unroll
            for (int j = 0; j < 4; ++j) {
                int idx = sub - j - ((j2b + j >= 48) ? 48 : 0);
                float sv = st[s][j] + bias_l[idx];
                st[s][j] = sv;
                mx = fmaxf(mx, sv);
            }
        }
        mx = fmaxf(mx, __shfl_xor(mx, 16));
        mx = fmaxf(mx, __shfl_xor(mx, 32));
        float mn = fmaxf(m_st, mx);
        float rs = 0.f;
        #pragma unroll
        for (int s = 0; s < 4; ++s)
            #pragma unroll
            for (int j = 0; j < 4; ++j) {
                float e = __expf(st[s][j] - mn);
                st[s][j] = e;
                rs += e;
            }
        rs += __shfl_xor(rs, 16);
        rs += __shfl_xor(rs, 32);
        float sc = __expf(m_st - mn);
        l_st = l_st * sc + rs;
        m_st = mn;
        float scr[4];
        #pragma unroll
        for (int j = 0; j < 4; ++j) scr[j] = __shfl(sc, 4 * g + j);
        #pragma unroll
        for (int j = 0; j < 4; ++j) { o0[j] *= scr[j]; o1[j] *= scr[j]; }
        // P -> LDS (transpose back to [q][kv])
        #pragma unroll
        for (int s = 0; s < 4; ++s) {
            bf16x4 pk = { (__bf16)st[s][0], (__bf16)st[s][1], (__bf16)st[s][2], (__bf16)st[s][3] };
            *reinterpret_cast<bf16x4*>(&P_lds[w][l15][16 * s + 4 * g]) = pk;
        }
        // PV
        #pragma unroll
        for (int hh = 0; hh < 2; ++hh) {
            bf16x8 pf = *reinterpret_cast<const bf16x8*>(&P_lds[w][l15][32 * hh + 8 * g]);
            o0 = MFMA16(pf, vf[hh], o0);
            o1 = MFMA16(pf, vf[2 + hh], o1);
        }
    }

    // write partials
    size_t mb = (size_t)(kvq * 8 + h) * NSEQ;
    if (g == 0) { Pm[mb + qrow] = m_st; Pl[mb + qrow] = l_st; }
    #pragma unroll
    for (int dt = 0; dt < 2; ++dt)
        #pragma unroll
        for (int j = 0; j < 4; ++j) {
            int row = q0 + w * 16 + 4 * g + j;
            PO[(mb + row) * 32 + 16 * dt + l15] =
                __float2bfloat16(dt == 0 ? o0[j] : o1[j]);
        }
}

// ---------------- softmax partial merge ----------------
__global__ __launch_bounds__(256) void attn_merge_kernel(
    const __hip_bfloat16* __restrict__ PO, const float* __restrict__ Pm,
    const float* __restrict__ Pl, __hip_bfloat16* __restrict__ Ob)
{
    int gid = blockIdx.x * 256 + threadIdx.x;       // 8*2304*32
    int d = gid & 31;
    int hq = gid >> 5;
    int q = hq % 2304;
    int h = hq / 2304;
    float m[4], l[4];
    #pragma unroll
    for (int k = 0; k < 4; ++k) {
        size_t mb = (size_t)(k * 8 + h) * NSEQ + q;
        m[k] = Pm[mb]; l[k] = Pl[mb];
    }
    float M = fmaxf(fmaxf(m[0], m[1]), fmaxf(m[2], m[3]));
    float L = 0.f, o = 0.f;
    #pragma unroll
    for (int k = 0; k < 4; ++k) {
        float a = __expf(m[k] - M);
        L += a * l[k];
        o += a * __bfloat162float(PO[((size_t)(k * 8 + h) * NSEQ + q) * 32 + d]);
    }
    Ob[(size_t)q * 256 + h * 32 + d] = __float2bfloat16(o / L);
}

// ---------------- launch ----------------
extern "C" void kernel_launch(void* const* d_in, const int* in_sizes, int n_in,
                              void* d_out, int out_size, void* d_ws, size_t ws_size,
                              hipStream_t stream)
{
    const float* x      = (const float*)d_in[0];
    const float* gamma1 = (const float*)d_in[1];
    const float* beta1  = (const float*)d_in[2];
    const float* w_qkv  = (const float*)d_in[3];
    const float* w_proj = (const float*)d_in[4];
    const float* b_proj = (const float*)d_in[5];
    const float* btab   = (const float*)d_in[6];
    const float* gamma2 = (const float*)d_in[7];
    const float* beta2  = (const float*)d_in[8];
    const float* w_fc1  = (const float*)d_in[9];
    const float* b_fc1  = (const float*)d_in[10];
    const float* w_fc2  = (const float*)d_in[11];
    const float* b_fc2  = (const float*)d_in[12];
    // d_in[13] rel_idx: recomputed analytically in-kernel.

    char* ws = (char*)d_ws;
    size_t off = 0;
    auto alloc = [&](size_t bytes) -> void* {
        void* p = ws + off;
        off += (bytes + 255) & ~(size_t)255;
        return p;
    };
    __hip_bfloat16* wqkvT = (__hip_bfloat16*)alloc((size_t)768 * 256 * 2);
    __hip_bfloat16* wprojT= (__hip_bfloat16*)alloc((size_t)256 * 256 * 2);
    __hip_bfloat16* wfc1T = (__hip_bfloat16*)alloc((size_t)1024 * 256 * 2);
    __hip_bfloat16* wfc2T = (__hip_bfloat16*)alloc((size_t)256 * 1024 * 2);
    float*          btabT = (float*)alloc((size_t)8 * 9025 * 4);
    __hip_bfloat16* t1    = (__hip_bfloat16*)alloc((size_t)NSEQ * 256 * 2);
    __hip_bfloat16* Qb    = (__hip_bfloat16*)alloc((size_t)8 * NSEQ * 32 * 2);
    __hip_bfloat16* Kbuf  = (__hip_bfloat16*)alloc((size_t)8 * NSEQ * 32 * 2);
    __hip_bfloat16* Vt    = (__hip_bfloat16*)alloc((size_t)8 * 32 * NSEQ * 2);
    __hip_bfloat16* Ob    = (__hip_bfloat16*)alloc((size_t)NSEQ * 256 * 2);
    float*          x2    = (float*)alloc((size_t)NSEQ * 256 * 4);
    __hip_bfloat16* t2    = (__hip_bfloat16*)alloc((size_t)NSEQ * 256 * 2);
    float*          Pm    = (float*)alloc((size_t)4 * 8 * NSEQ * 4);
    float*          Pl    = (float*)alloc((size_t)4 * 8 * NSEQ * 4);
    // PO (bf16, 4*8*2304*32 = 4.72 MB) aliases hb (2304*1024 bf16 = 4.72 MB):
    // PO dead after merge; hb first written by fc1 (later). No overlap in time.
    __hip_bfloat16* PO    = (__hip_bfloat16*)alloc((size_t)4 * 8 * NSEQ * 32 * 2);
    __hip_bfloat16* hb    = PO;

    transpose_w_kernel<<<dim3(839), dim3(256), 0, stream>>>(
        w_qkv, w_proj, w_fc1, w_fc2, btab, wqkvT, wprojT, wfc1T, wfc2T, btabT);

    ln_kernel<<<dim3(NSEQ), dim3(256), 0, stream>>>(x, gamma1, beta1, t1);

    // QKV: M=2304 N=768 K=256, 64x64 blocks
    gemm_kernel<0, 768, 256, 2, 2, 2, 2><<<dim3(12, 36), dim3(256), 0, stream>>>(
        t1, wqkvT, nullptr, nullptr, Qb, Kbuf, Vt);

    attn_kernel<<<dim3(1152), dim3(256), 0, stream>>>(Qb, Kbuf, Vt, btabT, Pm, Pl, PO);

    attn_merge_kernel<<<dim3(2304), dim3(256), 0, stream>>>(PO, Pm, Pl, Ob);

    // proj: M=2304 N=256 K=256, 64x16 blocks (more waves)
    gemm_kernel<1, 256, 256, 1, 1, 4, 1><<<dim3(16, 36), dim3(256), 0, stream>>>(
        Ob, wprojT, b_proj, x, x2, nullptr, nullptr);

    ln_kernel<<<dim3(NSEQ), dim3(256), 0, stream>>>(x2, gamma2, beta2, t2);

    // fc1: M=2304 N=1024 K=256, 64x64 blocks
    gemm_kernel<2, 1024, 256, 2, 2, 2, 2><<<dim3(16, 36), dim3(256), 0, stream>>>(
        t2, wfc1T, b_fc1, nullptr, hb, nullptr, nullptr);

    // fc2: M=2304 N=256 K=1024, 64x16 blocks
    gemm_kernel<3, 256, 1024, 1, 1, 4, 1><<<dim3(16, 36), dim3(256), 0, stream>>>(
        hb, wfc2T, b_fc2, x2, d_out, nullptr, nullptr);
}

// Round 3
// 192.199 us; speedup vs baseline: 1.0676x; 1.0139x over previous
//
#include <hip/hip_runtime.h>
#include <hip/hip_bf16.h>

// ---------------- types ----------------
typedef __bf16 bf16x8 __attribute__((__ext_vector_type__(8)));
typedef __bf16 bf16x4 __attribute__((__ext_vector_type__(4)));
typedef float  f32x4  __attribute__((__ext_vector_type__(4)));

#define MFMA16(a, b, c) __builtin_amdgcn_mfma_f32_16x16x32_bf16((a), (b), (c), 0, 0, 0)

static constexpr int   NSEQ  = 2304;   // 48*48
static constexpr float SCALE = 0.17677669529663687f;  // 32^-0.5
static constexpr int   KVS   = 6;      // kv split factor

// XOR swizzle for [rows][256] bf16 LDS tiles (row stride 512B).
// Conflict-free for ds_read_b128 of A-fragments (row varies per lane).
#define SWZ(row, colByte) ((row) * 512 + ((colByte) ^ (((row) & 7) << 4)))

// ---------------- weight transpose + f32->bf16 (+ bias table transpose) ----------------
__global__ __launch_bounds__(256) void prep_kernel(
    const float* __restrict__ wqkv, const float* __restrict__ wproj,
    const float* __restrict__ wfc1, const float* __restrict__ wfc2,
    const float* __restrict__ btab,
    __hip_bfloat16* __restrict__ oqkv, __hip_bfloat16* __restrict__ oproj,
    __hip_bfloat16* __restrict__ ofc1, __hip_bfloat16* __restrict__ ofc2,
    float* __restrict__ btabT)
{
    int b = blockIdx.x;
    int tid = threadIdx.x;
    if (b >= 768) {   // bias table [9025][8] -> [8][9025]
        int base = (b - 768) * 1024;
        for (int k = tid; k < 1024; k += 256) {
            int e = base + k;
            if (e < 72200) { int i = e >> 3, hh = e & 7; btabT[hh * 9025 + i] = btab[e]; }
        }
        return;
    }
    const float* src; __hip_bfloat16* dst; int K, N, t;
    if (b < 192)      { src = wqkv;  dst = oqkv;  K = 256;  N = 768;  t = b;       }
    else if (b < 256) { src = wproj; dst = oproj; K = 256;  N = 256;  t = b - 192; }
    else if (b < 512) { src = wfc1;  dst = ofc1;  K = 256;  N = 1024; t = b - 256; }
    else              { src = wfc2;  dst = ofc2;  K = 1024; N = 256;  t = b - 512; }
    int ntn = N >> 5;
    int tk = t / ntn, tn = t % ntn;
    __shared__ float tile[32][33];
    int tx = tid & 31, ty = tid >> 5;   // 32 x 8
    #pragma unroll
    for (int r = 0; r < 4; ++r)
        tile[ty + 8 * r][tx] = src[(size_t)(tk * 32 + ty + 8 * r) * N + tn * 32 + tx];
    __syncthreads();
    #pragma unroll
    for (int r = 0; r < 4; ++r)
        dst[(size_t)(tn * 32 + ty + 8 * r) * K + tk * 32 + tx] =
            __float2bfloat16(tile[tx][ty + 8 * r]);
}

// ---------------- fused LN1 + QKV GEMM ----------------
// grid (12,36), 256 thr. Block: 64 rows (LN'd into LDS) x 64 cols of [Q|K|V].
__global__ __launch_bounds__(256) void qkv_ln_kernel(
    const float* __restrict__ x, const float* __restrict__ g1,
    const float* __restrict__ b1, const __hip_bfloat16* __restrict__ BT,
    __hip_bfloat16* __restrict__ Qb, __hip_bfloat16* __restrict__ Kb,
    __hip_bfloat16* __restrict__ Vt)
{
    __shared__ char smem[64 * 512];    // A-tile [64][256] bf16 swizzled; reused as vtile
    int tid = threadIdx.x;
    int w = tid >> 6, lane = tid & 63, l15 = lane & 15, g = lane >> 4;
    int bm = blockIdx.y * 64, bn = blockIdx.x * 64;

    // --- LN prologue: 4 lanes per row ---
    {
        int row = tid >> 2;            // 0..63
        int part = tid & 3;
        const float* xr = x + (size_t)(bm + row) * 256 + part * 64;
        float vals[64];
        float s = 0.f, s2 = 0.f;
        #pragma unroll
        for (int i = 0; i < 16; ++i) {
            f32x4 v4 = *reinterpret_cast<const f32x4*>(xr + 4 * i);
            #pragma unroll
            for (int e = 0; e < 4; ++e) {
                vals[4 * i + e] = v4[e];
                s += v4[e]; s2 += v4[e] * v4[e];
            }
        }
        s  += __shfl_xor(s, 1);  s  += __shfl_xor(s, 2);
        s2 += __shfl_xor(s2, 1); s2 += __shfl_xor(s2, 2);
        float mu   = s * (1.f / 256.f);
        float var  = s2 * (1.f / 256.f) - mu * mu;
        float rstd = rsqrtf(var + 1e-5f);
        #pragma unroll
        for (int i = 0; i < 16; ++i) {
            int c = part * 64 + 4 * i;
            f32x4 gv = *reinterpret_cast<const f32x4*>(g1 + c);
            f32x4 bv = *reinterpret_cast<const f32x4*>(b1 + c);
            bf16x4 pk;
            #pragma unroll
            for (int e = 0; e < 4; ++e)
                pk[e] = (__bf16)((vals[4 * i + e] - mu) * rstd * gv[e] + bv[e]);
            *reinterpret_cast<bf16x4*>(smem + SWZ(row, c * 2)) = pk;
        }
    }
    __syncthreads();

    // --- GEMM: 2x2 waves, 2x2 frags each ---
    int wr = w >> 1, wc = w & 1;
    f32x4 acc[2][2];
    #pragma unroll
    for (int i = 0; i < 2; ++i)
        #pragma unroll
        for (int j = 0; j < 2; ++j) acc[i][j] = (f32x4){0.f, 0.f, 0.f, 0.f};
    const __hip_bfloat16* Brow = BT + (size_t)(bn + wc * 32 + l15) * 256 + 8 * g;
    #pragma unroll
    for (int kb = 0; kb < 256; kb += 32) {
        bf16x8 af[2], bfr[2];
        #pragma unroll
        for (int i = 0; i < 2; ++i)
            af[i] = *reinterpret_cast<const bf16x8*>(
                smem + SWZ(wr * 32 + 16 * i + l15, (kb + 8 * g) * 2));
        #pragma unroll
        for (int j = 0; j < 2; ++j)
            bfr[j] = *reinterpret_cast<const bf16x8*>(Brow + (size_t)16 * j * 256 + kb);
        #pragma unroll
        for (int i = 0; i < 2; ++i)
            #pragma unroll
            for (int j = 0; j < 2; ++j)
                acc[i][j] = MFMA16(af[i], bfr[j], acc[i][j]);
    }

    // --- epilogue ---
    if (bn >= 512) {   // V: LDS transpose for coalesced [h][d][n] stores
        __syncthreads();
        float* vtile = (float*)smem;   // [64][65]
        #pragma unroll
        for (int fi = 0; fi < 2; ++fi)
        #pragma unroll
        for (int fj = 0; fj < 2; ++fj)
        #pragma unroll
        for (int j = 0; j < 4; ++j)
            vtile[(32 * wr + 16 * fi + 4 * g + j) * 65 + 32 * wc + 16 * fj + l15] =
                acc[fi][fj][j];
        __syncthreads();
        for (int e = tid; e < 4096; e += 256) {
            int mi = e & 63, ni = e >> 6;
            int n = bn + ni;
            int h = (n >> 5) & 7, d = n & 31;
            Vt[(size_t)(h * 32 + d) * NSEQ + bm + mi] = __float2bfloat16(vtile[mi * 65 + ni]);
        }
        return;
    }
    #pragma unroll
    for (int fi = 0; fi < 2; ++fi)
    #pragma unroll
    for (int fj = 0; fj < 2; ++fj)
    #pragma unroll
    for (int j = 0; j < 4; ++j) {
        int m = bm + 32 * wr + 16 * fi + 4 * g + j;
        int n = bn + 32 * wc + 16 * fj + l15;
        float v = acc[fi][fj][j];
        int which = n >> 8, h = (n >> 5) & 7, d = n & 31;
        if (which == 0) Qb[((size_t)(h * NSEQ + m) << 5) + d] = __float2bfloat16(v * SCALE);
        else            Kb[((size_t)(h * NSEQ + m) << 5) + d] = __float2bfloat16(v);
    }
}

// ---------------- flash attention, kv split 6 ways across blocks ----------------
// grid: 8 heads * 36 q-tiles * 6 kv-sixths = 1728 blocks; 4 waves.
__global__ __launch_bounds__(256) void attn_kernel(
    const __hip_bfloat16* __restrict__ Q,
    const __hip_bfloat16* __restrict__ Kb,
    const __hip_bfloat16* __restrict__ Vt,     // [8][32][2304]
    const float* __restrict__ btabT,           // [8][9025]
    float* __restrict__ Pm, float* __restrict__ Pl,
    __hip_bfloat16* __restrict__ PO)           // [6][8][2304][32]
{
    __shared__ float bias_l[10 * 96];
    __shared__ __hip_bfloat16 P_lds[4][16][72];

    int bid = blockIdx.x;
    int h = bid / (36 * KVS);
    int r = bid - h * (36 * KVS);
    int qt = r / KVS, kvq = r - qt * KVS;
    int tid = threadIdx.x;
    int w = tid >> 6, lane = tid & 63, l15 = lane & 15, g = lane >> 4;

    int q0 = qt * 64;
    int i1min = q0 / 48, i1max = (q0 + 63) / 48;
    int i2min = kvq * 8;                 // 384 kv rows = 8 image rows exactly
    int dimin = i1min - (i2min + 7);
    int nrow = (i1max - i1min) + 8;      // <= 9

    for (int i = tid; i < nrow * 95; i += 256) {
        int rr = i / 95, cc = i - rr * 95;
        bias_l[rr * 96 + cc] = btabT[h * 9025 + (dimin + rr + 47) * 95 + cc];
    }
    __syncthreads();

    int qrow = q0 + w * 16 + l15;
    int i1 = qrow / 48, j1 = qrow - i1 * 48;
    int laneBase = (i1 - dimin) * 96 + j1 + 47;
    bf16x8 qf = *reinterpret_cast<const bf16x8*>(Q + ((size_t)(h * NSEQ + qrow) << 5) + 8 * g);

    float m_st = -1e30f, l_st = 0.f;
    f32x4 o0 = (f32x4){0.f, 0.f, 0.f, 0.f};
    f32x4 o1 = (f32x4){0.f, 0.f, 0.f, 0.f};
    const f32x4 zero = (f32x4){0.f, 0.f, 0.f, 0.f};
    int kvbase = kvq * 384;

    for (int t = 0; t < 6; ++t) {
        int kv0 = kvbase + t * 64;
        bf16x8 vf[4];
        #pragma unroll
        for (int u = 0; u < 4; ++u) {
            int dt = u >> 1, hh = u & 1;
            vf[u] = *reinterpret_cast<const bf16x8*>(
                Vt + (size_t)((h << 5) + 16 * dt + l15) * NSEQ + kv0 + 32 * hh + 8 * g);
        }
        f32x4 st[4];
        #pragma unroll
        for (int s = 0; s < 4; ++s) {
            bf16x8 kf = *reinterpret_cast<const bf16x8*>(
                Kb + ((size_t)(h * NSEQ + kv0 + 16 * s + l15) << 5) + 8 * g);
            st[s] = MFMA16(kf, qf, zero);   // S^T[kv][q]
        }
        float mx = -1e30f;
        #pragma unroll
        for (int s = 0; s < 4; ++s) {
            int kvb = kv0 + 16 * s + 4 * g;
            int i2 = kvb / 48;
            int j2b = kvb - 48 * i2;
            int sub = laneBase - i2 * 96 - j2b;
            #pragma unroll
            for (int j = 0; j < 4; ++j) {
                int idx = sub - j - ((j2b + j >= 48) ? 48 : 0);
                float sv = st[s][j] + bias_l[idx];
                st[s][j] = sv;
                mx = fmaxf(mx, sv);
            }
        }
        mx = fmaxf(mx, __shfl_xor(mx, 16));
        mx = fmaxf(mx, __shfl_xor(mx, 32));
        float mn = fmaxf(m_st, mx);
        float rs = 0.f;
        #pragma unroll
        for (int s = 0; s < 4; ++s)
            #pragma unroll
            for (int j = 0; j < 4; ++j) {
                float e = __expf(st[s][j] - mn);
                st[s][j] = e;
                rs += e;
            }
        rs += __shfl_xor(rs, 16);
        rs += __shfl_xor(rs, 32);
        float sc = __expf(m_st - mn);
        l_st = l_st * sc + rs;
        m_st = mn;
        float scr[4];
        #pragma unroll
        for (int j = 0; j < 4; ++j) scr[j] = __shfl(sc, 4 * g + j);
        #pragma unroll
        for (int j = 0; j < 4; ++j) { o0[j] *= scr[j]; o1[j] *= scr[j]; }
        #pragma unroll
        for (int s = 0; s < 4; ++s) {
            bf16x4 pk = { (__bf16)st[s][0], (__bf16)st[s][1], (__bf16)st[s][2], (__bf16)st[s][3] };
            *reinterpret_cast<bf16x4*>(&P_lds[w][l15][16 * s + 4 * g]) = pk;
        }
        #pragma unroll
        for (int hh = 0; hh < 2; ++hh) {
            bf16x8 pf = *reinterpret_cast<const bf16x8*>(&P_lds[w][l15][32 * hh + 8 * g]);
            o0 = MFMA16(pf, vf[hh], o0);
            o1 = MFMA16(pf, vf[2 + hh], o1);
        }
    }

    size_t mb = (size_t)(kvq * 8 + h) * NSEQ;
    if (g == 0) { Pm[mb + qrow] = m_st; Pl[mb + qrow] = l_st; }
    #pragma unroll
    for (int dt = 0; dt < 2; ++dt)
        #pragma unroll
        for (int j = 0; j < 4; ++j) {
            int row = q0 + w * 16 + 4 * g + j;
            PO[(mb + row) * 32 + 16 * dt + l15] =
                __float2bfloat16(dt == 0 ? o0[j] : o1[j]);
        }
}

// ---------------- fused merge + proj + residual + LN2 ----------------
// grid 144 blocks (16 rows each), 512 thr = 8 waves (one 32-col slice each).
__global__ __launch_bounds__(512) void proj_kernel(
    const __hip_bfloat16* __restrict__ PO, const float* __restrict__ Pm,
    const float* __restrict__ Pl, const __hip_bfloat16* __restrict__ BT,
    const float* __restrict__ bproj, const float* __restrict__ x,
    const float* __restrict__ g2, const float* __restrict__ b2,
    float* __restrict__ x2, __hip_bfloat16* __restrict__ t2)
{
    __shared__ char smem[16 * 512];    // merged A-tile [16][256] bf16 swizzled
    __shared__ float redS[8][16], redQ[8][16], muA[16], rsA[16];
    int tid = threadIdx.x;
    int q0 = blockIdx.x * 16;

    // --- merge prologue ---
    {
        int row = tid >> 5;            // 0..15
        int c0  = (tid & 31) * 8;
        int h = c0 >> 5, d = c0 & 31;
        float m[KVS], l[KVS], a[KVS];
        #pragma unroll
        for (int k = 0; k < KVS; ++k) {
            size_t mb = (size_t)(k * 8 + h) * NSEQ + q0 + row;
            m[k] = Pm[mb]; l[k] = Pl[mb];
        }
        float M = m[0];
        #pragma unroll
        for (int k = 1; k < KVS; ++k) M = fmaxf(M, m[k]);
        float L = 0.f;
        #pragma unroll
        for (int k = 0; k < KVS; ++k) { a[k] = __expf(m[k] - M); L += a[k] * l[k]; }
        float inv = 1.f / L;
        float o[8] = {0.f, 0.f, 0.f, 0.f, 0.f, 0.f, 0.f, 0.f};
        #pragma unroll
        for (int k = 0; k < KVS; ++k) {
            bf16x8 po = *reinterpret_cast<const bf16x8*>(
                PO + ((size_t)(k * 8 + h) * NSEQ + q0 + row) * 32 + d);
            #pragma unroll
            for (int e = 0; e < 8; ++e) o[e] += a[k] * (float)po[e];
        }
        bf16x8 pk;
        #pragma unroll
        for (int e = 0; e < 8; ++e) pk[e] = (__bf16)(o[e] * inv);
        *reinterpret_cast<bf16x8*>(smem + SWZ(row, c0 * 2)) = pk;
    }
    __syncthreads();

    // --- GEMM: wave w covers cols w*32..+31 (FN=2, FM=1) ---
    int w = tid >> 6, lane = tid & 63, l15 = lane & 15, g = lane >> 4;
    f32x4 acc[2];
    acc[0] = (f32x4){0.f, 0.f, 0.f, 0.f};
    acc[1] = (f32x4){0.f, 0.f, 0.f, 0.f};
    const __hip_bfloat16* Brow = BT + (size_t)(w * 32 + l15) * 256 + 8 * g;
    #pragma unroll
    for (int kb = 0; kb < 256; kb += 32) {
        bf16x8 af = *reinterpret_cast<const bf16x8*>(smem + SWZ(l15, (kb + 8 * g) * 2));
        #pragma unroll
        for (int fj = 0; fj < 2; ++fj) {
            bf16x8 bfr = *reinterpret_cast<const bf16x8*>(Brow + (size_t)16 * fj * 256 + kb);
            acc[fj] = MFMA16(af, bfr, acc[fj]);
        }
    }

    // --- epilogue: residual + LN2 ---
    float rr[2][4];
    float s[4] = {0.f, 0.f, 0.f, 0.f}, sq[4] = {0.f, 0.f, 0.f, 0.f};
    #pragma unroll
    for (int fj = 0; fj < 2; ++fj)
        #pragma unroll
        for (int j = 0; j < 4; ++j) {
            int mrow = 4 * g + j;
            int n = w * 32 + 16 * fj + l15;
            float v = acc[fj][j] + bproj[n] + x[(size_t)(q0 + mrow) * 256 + n];
            x2[(size_t)(q0 + mrow) * 256 + n] = v;
            rr[fj][j] = v;
            s[j] += v; sq[j] += v * v;
        }
    #pragma unroll
    for (int mask = 1; mask <= 8; mask <<= 1)
        #pragma unroll
        for (int j = 0; j < 4; ++j) {
            s[j]  += __shfl_xor(s[j],  mask);
            sq[j] += __shfl_xor(sq[j], mask);
        }
    if (l15 == 0)
        #pragma unroll
        for (int j = 0; j < 4; ++j) { redS[w][4 * g + j] = s[j]; redQ[w][4 * g + j] = sq[j]; }
    __syncthreads();
    if (tid < 16) {
        float S = 0.f, Qq = 0.f;
        #pragma unroll
        for (int ww = 0; ww < 8; ++ww) { S += redS[ww][tid]; Qq += redQ[ww][tid]; }
        float mu = S * (1.f / 256.f);
        float var = Qq * (1.f / 256.f) - mu * mu;
        muA[tid] = mu;
        rsA[tid] = rsqrtf(var + 1e-5f);
    }
    __syncthreads();
    #pragma unroll
    for (int fj = 0; fj < 2; ++fj)
        #pragma unroll
        for (int j = 0; j < 4; ++j) {
            int mrow = 4 * g + j;
            int n = w * 32 + 16 * fj + l15;
            float tv = (rr[fj][j] - muA[mrow]) * rsA[mrow] * g2[n] + b2[n];
            t2[(size_t)(q0 + mrow) * 256 + n] = __float2bfloat16(tv);
        }
}

// ---------------- MLP GEMMs: C[M,N] = A[M,K] @ BT[N,K]^T ----------------
// EPI 2: fc1+bias+gelu(bf16 out)  3: fc2+bias+residual(f32 out)
template <int EPI, int NN, int KK, int FM, int FN, int WR, int WC>
__global__ __launch_bounds__(256) void gemm_kernel(
    const __hip_bfloat16* __restrict__ A,
    const __hip_bfloat16* __restrict__ BT,
    const float* __restrict__ bias,
    const float* __restrict__ resid,
    void* __restrict__ out0)
{
    constexpr int BM = WR * FM * 16, BN = WC * FN * 16;
    int bm = blockIdx.y * BM, bn = blockIdx.x * BN;
    int tid = threadIdx.x;
    int w = tid >> 6, lane = tid & 63, l15 = lane & 15, g = lane >> 4;
    int wr = w / WC, wc = w % WC;

    f32x4 acc[FM][FN];
    #pragma unroll
    for (int i = 0; i < FM; ++i)
        #pragma unroll
        for (int j = 0; j < FN; ++j) acc[i][j] = (f32x4){0.f, 0.f, 0.f, 0.f};

    const __hip_bfloat16* Arow = A  + (size_t)(bm + wr * FM * 16 + l15) * KK + 8 * g;
    const __hip_bfloat16* Brow = BT + (size_t)(bn + wc * FN * 16 + l15) * KK + 8 * g;

    #pragma unroll
    for (int kb = 0; kb < KK; kb += 32) {
        bf16x8 af[FM], bfr[FN];
        #pragma unroll
        for (int i = 0; i < FM; ++i)
            af[i] = *reinterpret_cast<const bf16x8*>(Arow + (size_t)16 * i * KK + kb);
        #pragma unroll
        for (int j = 0; j < FN; ++j)
            bfr[j] = *reinterpret_cast<const bf16x8*>(Brow + (size_t)16 * j * KK + kb);
        #pragma unroll
        for (int i = 0; i < FM; ++i)
            #pragma unroll
            for (int j = 0; j < FN; ++j)
                acc[i][j] = MFMA16(af[i], bfr[j], acc[i][j]);
    }

    #pragma unroll
    for (int fi = 0; fi < FM; ++fi)
    #pragma unroll
    for (int fj = 0; fj < FN; ++fj)
    #pragma unroll
    for (int j = 0; j < 4; ++j) {
        int m = bm + wr * FM * 16 + 16 * fi + 4 * g + j;
        int n = bn + wc * FN * 16 + 16 * fj + l15;
        float v = acc[fi][fj][j];
        if constexpr (EPI == 2) {
            float r = v + bias[n];
            r = 0.5f * r * (1.f + erff(r * 0.70710678118654752f));
            ((__hip_bfloat16*)out0)[(size_t)m * NN + n] = __float2bfloat16(r);
        } else {
            ((float*)out0)[(size_t)m * 256 + n] = v + bias[n] + resid[(size_t)m * 256 + n];
        }
    }
}

// ---------------- launch ----------------
extern "C" void kernel_launch(void* const* d_in, const int* in_sizes, int n_in,
                              void* d_out, int out_size, void* d_ws, size_t ws_size,
                              hipStream_t stream)
{
    const float* x      = (const float*)d_in[0];
    const float* gamma1 = (const float*)d_in[1];
    const float* beta1  = (const float*)d_in[2];
    const float* w_qkv  = (const float*)d_in[3];
    const float* w_proj = (const float*)d_in[4];
    const float* b_proj = (const float*)d_in[5];
    const float* btab   = (const float*)d_in[6];
    const float* gamma2 = (const float*)d_in[7];
    const float* beta2  = (const float*)d_in[8];
    const float* w_fc1  = (const float*)d_in[9];
    const float* b_fc1  = (const float*)d_in[10];
    const float* w_fc2  = (const float*)d_in[11];
    const float* b_fc2  = (const float*)d_in[12];
    // d_in[13] rel_idx: recomputed analytically in-kernel.

    char* ws = (char*)d_ws;
    size_t off = 0;
    auto alloc = [&](size_t bytes) -> void* {
        void* p = ws + off;
        off += (bytes + 255) & ~(size_t)255;
        return p;
    };
    __hip_bfloat16* wqkvT = (__hip_bfloat16*)alloc((size_t)768 * 256 * 2);
    __hip_bfloat16* wprojT= (__hip_bfloat16*)alloc((size_t)256 * 256 * 2);
    __hip_bfloat16* wfc1T = (__hip_bfloat16*)alloc((size_t)1024 * 256 * 2);
    __hip_bfloat16* wfc2T = (__hip_bfloat16*)alloc((size_t)256 * 1024 * 2);
    float*          btabT = (float*)alloc((size_t)8 * 9025 * 4);
    __hip_bfloat16* Qb    = (__hip_bfloat16*)alloc((size_t)8 * NSEQ * 32 * 2);
    __hip_bfloat16* Kbuf  = (__hip_bfloat16*)alloc((size_t)8 * NSEQ * 32 * 2);
    __hip_bfloat16* Vt    = (__hip_bfloat16*)alloc((size_t)8 * 32 * NSEQ * 2);
    float*          x2    = (float*)alloc((size_t)NSEQ * 256 * 4);
    __hip_bfloat16* t2    = (__hip_bfloat16*)alloc((size_t)NSEQ * 256 * 2);
    float*          Pm    = (float*)alloc((size_t)KVS * 8 * NSEQ * 4);
    float*          Pl    = (float*)alloc((size_t)KVS * 8 * NSEQ * 4);
    __hip_bfloat16* PO    = (__hip_bfloat16*)alloc((size_t)KVS * 8 * NSEQ * 32 * 2);
    __hip_bfloat16* hb    = (__hip_bfloat16*)alloc((size_t)NSEQ * 1024 * 2);

    prep_kernel<<<dim3(839), dim3(256), 0, stream>>>(
        w_qkv, w_proj, w_fc1, w_fc2, btab, wqkvT, wprojT, wfc1T, wfc2T, btabT);

    qkv_ln_kernel<<<dim3(12, 36), dim3(256), 0, stream>>>(
        x, gamma1, beta1, wqkvT, Qb, Kbuf, Vt);

    attn_kernel<<<dim3(8 * 36 * KVS), dim3(256), 0, stream>>>(
        Qb, Kbuf, Vt, btabT, Pm, Pl, PO);

    proj_kernel<<<dim3(144), dim3(512), 0, stream>>>(
        PO, Pm, Pl, wprojT, b_proj, x, gamma2, beta2, x2, t2);

    gemm_kernel<2, 1024, 256, 2, 2, 2, 2><<<dim3(16, 36), dim3(256), 0, stream>>>(
        t2, wfc1T, b_fc1, nullptr, hb);

    gemm_kernel<3, 256, 1024, 1, 1, 4, 1><<<dim3(16, 36), dim3(256), 0, stream>>>(
        hb, wfc2T, b_fc2, x2, d_out);
}